// Round 9
// baseline (146.057 us; speedup 1.0000x reference)
//
#include <hip/hip_runtime.h>
#include <hip/hip_bf16.h>

// Problem constants
#define B_ 2
#define S_ 1024
#define I_ 512
#define C_ 32
#define EPS_ 1e-5f

// ---------------------------------------------------------------------------
// a_t/b_t layout (v9): s-blocked slabs  [b][sg][c][i][s_l], sg = s>>6.
//   s_l: 64 elems contiguous (128 B rows)
//   i  : stride 64 elems (rows dense -> GEMM stages sequential 128B rows)
//   c  : stride 32800 elems (65,600 B; +64B pad kills 64-KiB channel alias)
//   sg : stride 32*CST+32; b: 16*SGST
// An ln_proj block's whole output lands in ONE ~2.1 MiB slab (DRAM-local).
// ---------------------------------------------------------------------------
#define IST 64
#define CST (512 * 64 + 32)        // 32800 elems
#define SGST (32 * CST + 32)       // 1049632 elems
#define BST (16 * SGST)            // 16794112 elems

// GEMM tiling: 256x256 tile, 8 waves, BK=32, double-buffered.
#define GBM 256
#define GBN 256
#define BK 32
#define NT (S_ / BK)   // 32 K-steps

typedef __attribute__((ext_vector_type(8))) short bf16x8;   // 8 bf16 = 4 VGPRs (MFMA A/B frag)
typedef __attribute__((ext_vector_type(4))) short bf16x4;   // 4 bf16 = 8 B
typedef __attribute__((ext_vector_type(4))) float f32x4;    // MFMA C/D frag

static __device__ __forceinline__ short f2bf(float f) {
    union { __hip_bfloat16 h; short s; } u;
    u.h = __float2bfloat16(f);
    return u.s;
}

// ---------------------------------------------------------------------------
// Pass 0 (v9): v8 structure (per-thread-row LN, acc-diet MFMA, single
// barrier) with the NEW slab output layout. Store instr = 8 segments x 128B
// at 65.6-KiB stride, all within one 2.1-MiB slab; grid is ig-fastest so
// concurrent blocks fill slabs densely (i-adjacent 512B runs per c).
//
// Round-8 post-mortem: occupancy 23->32% (reg diet worked) but dur pinned at
// ~82us -> latency theory dead. All variants shared ONE thing: c-plane
// writes scattered as 128-B chunks over 128 MiB -> DRAM write efficiency
// ~35%. This round tests exactly that (layout change only).
// ---------------------------------------------------------------------------
__global__ __launch_bounds__(256) void ln_proj_kernel(
    const float* __restrict__ m,
    const float* __restrict__ g, const float* __restrict__ beta,
    const float* __restrict__ Wa, const float* __restrict__ ba,
    const float* __restrict__ Wb, const float* __restrict__ bb,
    __hip_bfloat16* __restrict__ a_t, __hip_bfloat16* __restrict__ b_t)
{
    __shared__ __align__(16) __hip_bfloat16 mhf[8192];      // 16 KiB frag-linear mh
    __shared__ __align__(16) __hip_bfloat16 trb[4 * 2304];  // 18 KiB transpose (wave-private slices)

    const int tid  = threadIdx.x;
    const int lane = tid & 63;
    const int w    = tid >> 6;
    const int lo   = lane & 15;
    const int hi   = lane >> 4;

    const int blk = blockIdx.x;                 // ((b*16 + sg)*128 + ig)  (ig fastest)
    const int ig = blk & 127;
    const int sg = (blk >> 7) & 15;
    const int b  = blk >> 11;
    const int s0 = sg * 64;
    const int i0 = ig * 4;

    // thread <-> row: i_l = tid&3, s_l = tid>>2
    const int i_l = tid & 3;
    const int s_l = tid >> 2;

    // ---- issue own-row loads FIRST (8 independent float4) ----
    const float* mp = m + ((size_t)(b * S_ + s0 + s_l) * I_ + i0 + i_l) * C_;
    float4 mv[8];
#pragma unroll
    for (int v = 0; v < 8; ++v) mv[v] = reinterpret_cast<const float4*>(mp)[v];

    // ---- B-frags: Wa/Wb rows as bf16x8 (latency hidden under m-loads) ----
    bf16x8 bw[4];
    float biasv[4];
#pragma unroll
    for (int f = 0; f < 4; ++f) {
        const float* Wsrc = (f & 2) ? Wb : Wa;
        const float* bsrc = (f & 2) ? bb : ba;
        int c = (f & 1) * 16 + lo;
        const float* src = Wsrc + c * C_ + hi * 8;
        float4 u0 = *reinterpret_cast<const float4*>(src);
        float4 u1 = *reinterpret_cast<const float4*>(src + 4);
        bf16x8 ch;
        ch[0] = f2bf(u0.x); ch[1] = f2bf(u0.y); ch[2] = f2bf(u0.z); ch[3] = f2bf(u0.w);
        ch[4] = f2bf(u1.x); ch[5] = f2bf(u1.y); ch[6] = f2bf(u1.z); ch[7] = f2bf(u1.w);
        bw[f] = ch;
        biasv[f] = bsrc[c];
    }

    // ---- LN, pure register math ----
    float x[C_];
#pragma unroll
    for (int v = 0; v < 8; ++v) {
        x[4*v+0] = mv[v].x; x[4*v+1] = mv[v].y; x[4*v+2] = mv[v].z; x[4*v+3] = mv[v].w;
    }
    float mu = 0.f;
#pragma unroll
    for (int c = 0; c < C_; ++c) mu += x[c];
    mu *= (1.f / C_);
    float var = 0.f;
#pragma unroll
    for (int c = 0; c < C_; ++c) { float dd = x[c] - mu; var += dd * dd; }
    float rs = rsqrtf(var * (1.f / C_) + EPS_);
#pragma unroll
    for (int c = 0; c < C_; ++c) x[c] = (x[c] - mu) * rs * g[c] + beta[c];

    // ---- pack + swizzled frag-linear LDS write ----
    char* ldsb = reinterpret_cast<char*>(mhf);
    {
        const int pt   = i_l * 4 + (s_l >> 4);
        const int base = pt * 1024 + (s_l & 15) * 16;
        const int swzb = (i_l & 3) << 5;
#pragma unroll
        for (int ks = 0; ks < 4; ++ks) {
            bf16x8 ch;
#pragma unroll
            for (int e = 0; e < 8; ++e) ch[e] = f2bf(x[ks * 8 + e]);
            *reinterpret_cast<bf16x8*>(ldsb + ((base + ks * 256) ^ swzb)) = ch;
        }
    }
    __syncthreads();   // the ONLY barrier

    // ---- A-frag reads once (XOR wave-uniform: pt = w*4+q -> pt>>2 = w) ----
    bf16x8 af[4];
#pragma unroll
    for (int q = 0; q < 4; ++q) {
        int pt   = w * 4 + q;
        int byte = (pt * 1024 + lane * 16) ^ ((pt >> 2) << 5);
        af[q] = *reinterpret_cast<const bf16x8*>(ldsb + byte);
    }

    // ---- p-loop: 2 MFMAs live at a time, immediate transpose+store ----
    const size_t slab = (size_t)b * BST + (size_t)sg * SGST;
    __hip_bfloat16* trw = trb + w * 2304;       // wave-private, no barriers needed
#pragma unroll
    for (int p = 0; p < 2; ++p) {
#pragma unroll
        for (int q = 0; q < 4; ++q) {
#pragma unroll
            for (int fh = 0; fh < 2; ++fh) {
                int f = p * 2 + fh;
                f32x4 d = __builtin_amdgcn_mfma_f32_16x16x32_bf16(
                    af[q], bw[f], (f32x4){0.f, 0.f, 0.f, 0.f}, 0, 0, 0);
                bf16x4 v4;
#pragma unroll
                for (int r = 0; r < 4; ++r) v4[r] = f2bf(d[r] + biasv[f]);
                int c = fh * 16 + lo;
                int s = q * 16 + hi * 4;
                *reinterpret_cast<bf16x4*>(trw + c * 72 + s) = v4;
            }
        }
        __hip_bfloat16* outp = p ? b_t : a_t;
#pragma unroll
        for (int cg = 0; cg < 4; ++cg) {
            int c  = cg * 8 + (lane >> 3);
            int s8 = (lane & 7) * 8;
            bf16x8 vv = *reinterpret_cast<const bf16x8*>(trw + c * 72 + s8);
            size_t off = slab + (size_t)c * CST + (size_t)(i0 + w) * IST + s8;
            *reinterpret_cast<bf16x8*>(outp + off) = vv;   // 8 x 128B within one slab
        }
    }
}

// ---------------------------------------------------------------------------
// Pass 1 (v9): structure identical to v7/v8 (256x256 tiles, 8 waves, BK=32
// dbuf, gload_lds w=16, read-side XOR swizzle with source pre-swizzle, T1
// XCD swizzle, bf16 epilogue with 1/S folded). Only the STAGE addressing
// changed for the slab layout: rows are dense 128-B lines; per K-step t the
// source is slab(sg=t>>1) + row*128 + (t&1)*64.
// ---------------------------------------------------------------------------
__global__ __launch_bounds__(512, 2) void opm_gemm_kernel(
    const __hip_bfloat16* __restrict__ a_t,
    const __hip_bfloat16* __restrict__ b_t,
    __hip_bfloat16* __restrict__ outer)
{
    __shared__ __align__(16) __hip_bfloat16 sA[2][GBM * BK];  // 16 KiB per buf
    __shared__ __align__(16) __hip_bfloat16 sB[2][GBN * BK];  // total 64 KiB

    const int tid  = threadIdx.x;
    const int wave = tid >> 6;           // 0..7
    const int lane = tid & 63;
    // T1: 256 blocks % 8 == 0 -> bijective chunked swizzle (32 blocks/XCD)
    const int swz  = (blockIdx.x & 7) * 32 + (blockIdx.x >> 3);
    const int bc   = swz >> 2;           // (b*C + c), 0..63
    const int tile = swz & 3;            // 2x2 output tiles per GEMM
    const int i0   = (tile >> 1) * GBM;
    const int j0   = (tile & 1)  * GBN;

    const char* Ap = (const char*)(a_t + (size_t)(bc >> 5) * BST
                                       + (size_t)(bc & 31) * CST + (size_t)i0 * IST);
    const char* Bp = (const char*)(b_t + (size_t)(bc >> 5) * BST
                                       + (size_t)(bc & 31) * CST + (size_t)j0 * IST);

    f32x4 acc[8][4];
#pragma unroll
    for (int mI = 0; mI < 8; ++mI)
#pragma unroll
        for (int nI = 0; nI < 4; ++nI)
            acc[mI][nI] = (f32x4){0.f, 0.f, 0.f, 0.f};

    const int wr = wave >> 2;      // wave row (0..1): rows [wr*128, +128)
    const int wc = wave & 3;       // wave col (0..3): cols [wc*64, +64)
    const int half = lane >> 4;    // k-group
    const int lrow = lane & 15;

    // staging: thread -> (row = tid>>2, piece = tid&3); source piece
    // pre-swizzled by (row>>1)&3 so the read-side XOR lands linear (rule 21).
    const int row_me = tid >> 2;                       // 0..127
    const int kb_me  = (((tid & 3) ^ ((tid >> 3) & 3)) << 4);

#define STAGE(bufidx, t) do {                                                              \
        const size_t sgo = (size_t)((t) >> 1) * (SGST * 2);                                \
        const int    sho = ((t) & 1) * 64;                                                 \
        const char* gA0 = Ap + sgo + (size_t)row_me * 128 + sho + kb_me;                   \
        const char* gB0 = Bp + sgo + (size_t)row_me * 128 + sho + kb_me;                   \
        char* lA = (char*)(&sA[bufidx][0]) + tid * 16;                                     \
        char* lB = (char*)(&sB[bufidx][0]) + tid * 16;                                     \
        __builtin_amdgcn_global_load_lds((const __attribute__((address_space(1))) void*)gA0,              \
                                         (__attribute__((address_space(3))) void*)lA, 16, 0, 0);          \
        __builtin_amdgcn_global_load_lds((const __attribute__((address_space(1))) void*)(gA0 + 128*128),  \
                                         (__attribute__((address_space(3))) void*)(lA + 8192), 16, 0, 0); \
        __builtin_amdgcn_global_load_lds((const __attribute__((address_space(1))) void*)gB0,              \
                                         (__attribute__((address_space(3))) void*)lB, 16, 0, 0);          \
        __builtin_amdgcn_global_load_lds((const __attribute__((address_space(1))) void*)(gB0 + 128*128),  \
                                         (__attribute__((address_space(3))) void*)(lB + 8192), 16, 0, 0); \
    } while (0)

    STAGE(0, 0);
    asm volatile("s_waitcnt vmcnt(0)" ::: "memory");
    __syncthreads();

#pragma unroll 2
    for (int t = 0; t < NT; ++t) {
        const int cur = t & 1;
        if (t + 1 < NT) STAGE(cur ^ 1, t + 1);   // prefetch next K-slab

        const char* lA = (const char*)(&sA[cur][0]);
        const char* lB = (const char*)(&sB[cur][0]);
        bf16x8 af[8], bfr[4];
#pragma unroll
        for (int mI = 0; mI < 8; ++mI) {
            int row  = wr * 128 + mI * 16 + lrow;
            int byte = (row * 64 + half * 16) ^ (((row >> 1) & 3) << 4);
            af[mI] = *reinterpret_cast<const bf16x8*>(lA + byte);
        }
#pragma unroll
        for (int nI = 0; nI < 4; ++nI) {
            int row  = wc * 64 + nI * 16 + lrow;
            int byte = (row * 64 + half * 16) ^ (((row >> 1) & 3) << 4);
            bfr[nI] = *reinterpret_cast<const bf16x8*>(lB + byte);
        }
#pragma unroll
        for (int mI = 0; mI < 8; ++mI)
#pragma unroll
            for (int nI = 0; nI < 4; ++nI)
                acc[mI][nI] = __builtin_amdgcn_mfma_f32_16x16x32_bf16(af[mI], bfr[nI], acc[mI][nI], 0, 0, 0);

        __syncthreads();   // drains vmcnt+lgkmcnt (buffers safe to swap)
    }
#undef STAGE

    // C/D layout: col = lane&15 (from B), row = (lane>>4)*4 + reg (from A)
    __hip_bfloat16* Op = outer + (size_t)bc * (I_ * I_);
#pragma unroll
    for (int mI = 0; mI < 8; ++mI) {
        int ii = i0 + wr * 128 + mI * 16 + half * 4;
#pragma unroll
        for (int nI = 0; nI < 4; ++nI) {
            int jj = j0 + wc * 64 + nI * 16 + lrow;
#pragma unroll
            for (int r = 0; r < 4; ++r)
                Op[(size_t)(ii + r) * I_ + jj] =
                    __float2bfloat16(acc[mI][nI][r] * (1.f / S_));
        }
    }
}

// ---------------------------------------------------------------------------
// Pass 2: out[b,i,j,c] = bo[c] + sum_c' Wo[c,c'] * outer_scaled[(b,c'),i,j]
// outer is bf16 with 1/S pre-folded (L2/L3-resident from pass 1).
// At roofline already: writes 64 MiB fp32 at ~6 TB/s.
// ---------------------------------------------------------------------------
__global__ __launch_bounds__(256) void wo_kernel(
    const __hip_bfloat16* __restrict__ outer,
    const float* __restrict__ Wo, const float* __restrict__ bo,
    float* __restrict__ out)
{
    int tid = blockIdx.x * 256 + threadIdx.x;   // ((b*I + i)*J + j)
    int j  = tid & (I_ - 1);
    int bi = tid >> 9;
    int i  = bi & (I_ - 1);
    int b  = bi >> 9;

    const __hip_bfloat16* ip = outer + ((size_t)(b * C_) * I_ + i) * I_ + j;
    float v[C_];
#pragma unroll
    for (int c = 0; c < C_; ++c) v[c] = __bfloat162float(ip[(size_t)c * (I_ * I_)]);

    float o[C_];
#pragma unroll
    for (int c = 0; c < C_; ++c) {
        float acc = bo[c];
#pragma unroll
        for (int k = 0; k < C_; ++k) acc = fmaf(Wo[c * C_ + k], v[k], acc);
        o[c] = acc;
    }

    float* op = out + (size_t)tid * C_;
#pragma unroll
    for (int vv = 0; vv < 8; ++vv) {
        float4 t4 = { o[4*vv+0], o[4*vv+1], o[4*vv+2], o[4*vv+3] };
        reinterpret_cast<float4*>(op)[vv] = t4;
    }
}

// ---------------------------------------------------------------------------
extern "C" void kernel_launch(void* const* d_in, const int* in_sizes, int n_in,
                              void* d_out, int out_size, void* d_ws, size_t ws_size,
                              hipStream_t stream) {
    const float* m    = (const float*)d_in[0];
    const float* ln_g = (const float*)d_in[1];
    const float* ln_b = (const float*)d_in[2];
    const float* Wa   = (const float*)d_in[3];
    const float* ba   = (const float*)d_in[4];
    const float* Wb   = (const float*)d_in[5];
    const float* bb   = (const float*)d_in[6];
    const float* Wo   = (const float*)d_in[7];
    const float* bo   = (const float*)d_in[8];
    float* out = (float*)d_out;

    const size_t AEL = (size_t)B_ * BST;            // elems per array (padded)
    const size_t nO  = (size_t)B_ * C_ * I_ * I_;   // 16,777,216 elems (32 MiB bf16)
    const size_t need = (AEL * 2 + nO) * sizeof(__hip_bfloat16);  // ~161 MiB
    if (ws_size < need) return;   // diagnostic: output stays zero -> ws too small

    __hip_bfloat16* a_t = (__hip_bfloat16*)d_ws;
    __hip_bfloat16* b_t = a_t + AEL;
    __hip_bfloat16* outer = b_t + AEL;

    ln_proj_kernel<<<B_ * 16 * 128, 256, 0, stream>>>(m, ln_g, ln_b, Wa, ba, Wb, bb, a_t, b_t);
    opm_gemm_kernel<<<B_ * C_ * 4, 512, 0, stream>>>(a_t, b_t, outer);
    wo_kernel<<<(B_ * I_ * I_) / 256, 256, 0, stream>>>(outer, Wo, bo, out);
}

// Round 10
// 145.319 us; speedup vs baseline: 1.0051x; 1.0051x over previous
//
#include <hip/hip_runtime.h>
#include <hip/hip_bf16.h>

// Problem constants
#define B_ 2
#define S_ 1024
#define I_ 512
#define C_ 32
#define EPS_ 1e-5f

// ---------------------------------------------------------------------------
// a_t/b_t layout (v9): s-blocked slabs  [b][sg][c][i][s_l], sg = s>>6.
// ---------------------------------------------------------------------------
#define IST 64
#define CST (512 * 64 + 32)        // 32800 elems
#define SGST (32 * CST + 32)       // 1049632 elems
#define BST (16 * SGST)            // 16794112 elems

// GEMM tiling: 256x256 tile, 8 waves, BK=32, double-buffered.
#define GBM 256
#define GBN 256
#define BK 32
#define NT (S_ / BK)   // 32 K-steps

typedef __attribute__((ext_vector_type(8))) short bf16x8;   // 8 bf16 = 4 VGPRs (MFMA A/B frag)
typedef __attribute__((ext_vector_type(4))) short bf16x4;   // 4 bf16 = 8 B
typedef __attribute__((ext_vector_type(4))) float f32x4;    // MFMA C/D frag

static __device__ __forceinline__ short f2bf(float f) {
    union { __hip_bfloat16 h; short s; } u;
    u.h = __float2bfloat16(f);
    return u.s;
}

// ---------------------------------------------------------------------------
// Pass 0 (v10): 4-slab blocks with cross-iteration software pipeline.
//
// Round-9 post-mortem: per-pipe arithmetic shows VALU 13us + HBM 33-40us +
// LDS 11us + MFMA 2us SUMS to the observed 80us -> zero inter-pipe overlap.
// Cause: one-shot ~2-3us blocks in lockstep phases; CU turns over 16 short
// WGs sequentially; launch/drain gaps dominate. All of rounds 5-9 changed
// phase CONTENT, never the block shape.
//
// v10: each block processes 4 consecutive sg slabs (grid 4096 -> 1024).
// Next slab's 8 float4 m-loads are issued BEFORE the current slab's
// barrier/MFMA/store phase (full unroll -> static regs), so load latency,
// VALU, LDS and store drain of adjacent iterations overlap. Weights loaded
// once per block (amortized 4x).
// ---------------------------------------------------------------------------
__global__ __launch_bounds__(256) void ln_proj_kernel(
    const float* __restrict__ m,
    const float* __restrict__ g, const float* __restrict__ beta,
    const float* __restrict__ Wa, const float* __restrict__ ba,
    const float* __restrict__ Wb, const float* __restrict__ bb,
    __hip_bfloat16* __restrict__ a_t, __hip_bfloat16* __restrict__ b_t)
{
    __shared__ __align__(16) __hip_bfloat16 mhf[8192];      // 16 KiB frag-linear mh
    __shared__ __align__(16) __hip_bfloat16 trb[4 * 2304];  // 18 KiB transpose (wave-private slices)

    const int tid  = threadIdx.x;
    const int lane = tid & 63;
    const int w    = tid >> 6;
    const int lo   = lane & 15;
    const int hi   = lane >> 4;

    const int blk = blockIdx.x;                 // ((b*4 + sgg)*128 + ig), ig fastest
    const int ig  = blk & 127;
    const int sgg = (blk >> 7) & 3;
    const int b   = blk >> 9;
    const int i0  = ig * 4;

    // thread <-> row: i_l = tid&3, s_l = tid>>2
    const int i_l = tid & 3;
    const int s_l = tid >> 2;

    const float* mrow = m + ((size_t)(b * S_ + sgg * 256 + s_l) * I_ + i0 + i_l) * C_;
    const size_t SSTEP = (size_t)64 * I_ * C_;      // advance 64 s positions

    // ---- issue slab-0 loads FIRST ----
    float4 mv[8];
#pragma unroll
    for (int v = 0; v < 8; ++v) mv[v] = reinterpret_cast<const float4*>(mrow)[v];

    // ---- B-frags: Wa/Wb rows as bf16x8 (latency hidden under m-loads) ----
    bf16x8 bw[4];
    float biasv[4];
#pragma unroll
    for (int f = 0; f < 4; ++f) {
        const float* Wsrc = (f & 2) ? Wb : Wa;
        const float* bsrc = (f & 2) ? bb : ba;
        int c = (f & 1) * 16 + lo;
        const float* src = Wsrc + c * C_ + hi * 8;
        float4 u0 = *reinterpret_cast<const float4*>(src);
        float4 u1 = *reinterpret_cast<const float4*>(src + 4);
        bf16x8 ch;
        ch[0] = f2bf(u0.x); ch[1] = f2bf(u0.y); ch[2] = f2bf(u0.z); ch[3] = f2bf(u0.w);
        ch[4] = f2bf(u1.x); ch[5] = f2bf(u1.y); ch[6] = f2bf(u1.z); ch[7] = f2bf(u1.w);
        bw[f] = ch;
        biasv[f] = bsrc[c];
    }

    char* ldsb = reinterpret_cast<char*>(mhf);
    __hip_bfloat16* trw = trb + w * 2304;       // wave-private transpose slice

#pragma unroll
    for (int ss = 0; ss < 4; ++ss) {
        const int sg = sgg * 4 + ss;

        // ---- LN on current slab (pure register math) ----
        float x[C_];
#pragma unroll
        for (int v = 0; v < 8; ++v) {
            x[4*v+0] = mv[v].x; x[4*v+1] = mv[v].y; x[4*v+2] = mv[v].z; x[4*v+3] = mv[v].w;
        }
        float mu = 0.f;
#pragma unroll
        for (int c = 0; c < C_; ++c) mu += x[c];
        mu *= (1.f / C_);
        float var = 0.f;
#pragma unroll
        for (int c = 0; c < C_; ++c) { float dd = x[c] - mu; var += dd * dd; }
        float rs = rsqrtf(var * (1.f / C_) + EPS_);
#pragma unroll
        for (int c = 0; c < C_; ++c) x[c] = (x[c] - mu) * rs * g[c] + beta[c];

        // ---- pack + swizzled frag-linear LDS write ----
        {
            const int pt   = i_l * 4 + (s_l >> 4);
            const int base = pt * 1024 + (s_l & 15) * 16;
            const int swzb = (i_l & 3) << 5;
#pragma unroll
            for (int ks = 0; ks < 4; ++ks) {
                bf16x8 ch;
#pragma unroll
                for (int e = 0; e < 8; ++e) ch[e] = f2bf(x[ks * 8 + e]);
                *reinterpret_cast<bf16x8*>(ldsb + ((base + ks * 256) ^ swzb)) = ch;
            }
        }

        // ---- issue NEXT slab's loads (independent; overlaps barrier/MFMA/store) ----
        if (ss < 3) {
            const float* mn = mrow + (size_t)(ss + 1) * SSTEP;
#pragma unroll
            for (int v = 0; v < 8; ++v) mv[v] = reinterpret_cast<const float4*>(mn)[v];
        }

        __syncthreads();   // mhf writes visible

        // ---- A-frag reads (XOR wave-uniform: pt = w*4+q -> pt>>2 = w) ----
        bf16x8 af[4];
#pragma unroll
        for (int q = 0; q < 4; ++q) {
            int pt   = w * 4 + q;
            int byte = (pt * 1024 + lane * 16) ^ ((pt >> 2) << 5);
            af[q] = *reinterpret_cast<const bf16x8*>(ldsb + byte);
        }

        __syncthreads();   // frag reads done -> next iter may overwrite mhf

        // ---- p-loop: 2 MFMAs live at a time, immediate transpose+store ----
        const size_t slab = (size_t)b * BST + (size_t)sg * SGST;
#pragma unroll
        for (int p = 0; p < 2; ++p) {
#pragma unroll
            for (int q = 0; q < 4; ++q) {
#pragma unroll
                for (int fh = 0; fh < 2; ++fh) {
                    int f = p * 2 + fh;
                    f32x4 d = __builtin_amdgcn_mfma_f32_16x16x32_bf16(
                        af[q], bw[f], (f32x4){0.f, 0.f, 0.f, 0.f}, 0, 0, 0);
                    bf16x4 v4;
#pragma unroll
                    for (int r = 0; r < 4; ++r) v4[r] = f2bf(d[r] + biasv[f]);
                    int c = fh * 16 + lo;
                    int s = q * 16 + hi * 4;
                    *reinterpret_cast<bf16x4*>(trw + c * 72 + s) = v4;
                }
            }
            __hip_bfloat16* outp = p ? b_t : a_t;
#pragma unroll
            for (int cg = 0; cg < 4; ++cg) {
                int c  = cg * 8 + (lane >> 3);
                int s8 = (lane & 7) * 8;
                bf16x8 vv = *reinterpret_cast<const bf16x8*>(trw + c * 72 + s8);
                size_t off = slab + (size_t)c * CST + (size_t)(i0 + w) * IST + s8;
                *reinterpret_cast<bf16x8*>(outp + off) = vv;   // 8 x 128B in one slab
            }
        }
    }
}

// ---------------------------------------------------------------------------
// Pass 1 (unchanged from v9): 64 independent GEMMs, 256x256 tiles, 8 waves,
// BK=32 dbuf via global_load_lds w=16, read-side XOR swizzle with source
// pre-swizzle (rule 21), T1 XCD swizzle, bf16 epilogue with 1/S folded.
// ---------------------------------------------------------------------------
__global__ __launch_bounds__(512, 2) void opm_gemm_kernel(
    const __hip_bfloat16* __restrict__ a_t,
    const __hip_bfloat16* __restrict__ b_t,
    __hip_bfloat16* __restrict__ outer)
{
    __shared__ __align__(16) __hip_bfloat16 sA[2][GBM * BK];  // 16 KiB per buf
    __shared__ __align__(16) __hip_bfloat16 sB[2][GBN * BK];  // total 64 KiB

    const int tid  = threadIdx.x;
    const int wave = tid >> 6;           // 0..7
    const int lane = tid & 63;
    // T1: 256 blocks % 8 == 0 -> bijective chunked swizzle (32 blocks/XCD)
    const int swz  = (blockIdx.x & 7) * 32 + (blockIdx.x >> 3);
    const int bc   = swz >> 2;           // (b*C + c), 0..63
    const int tile = swz & 3;            // 2x2 output tiles per GEMM
    const int i0   = (tile >> 1) * GBM;
    const int j0   = (tile & 1)  * GBN;

    const char* Ap = (const char*)(a_t + (size_t)(bc >> 5) * BST
                                       + (size_t)(bc & 31) * CST + (size_t)i0 * IST);
    const char* Bp = (const char*)(b_t + (size_t)(bc >> 5) * BST
                                       + (size_t)(bc & 31) * CST + (size_t)j0 * IST);

    f32x4 acc[8][4];
#pragma unroll
    for (int mI = 0; mI < 8; ++mI)
#pragma unroll
        for (int nI = 0; nI < 4; ++nI)
            acc[mI][nI] = (f32x4){0.f, 0.f, 0.f, 0.f};

    const int wr = wave >> 2;      // wave row (0..1): rows [wr*128, +128)
    const int wc = wave & 3;       // wave col (0..3): cols [wc*64, +64)
    const int half = lane >> 4;    // k-group
    const int lrow = lane & 15;

    const int row_me = tid >> 2;                       // 0..127
    const int kb_me  = (((tid & 3) ^ ((tid >> 3) & 3)) << 4);

#define STAGE(bufidx, t) do {                                                              \
        const size_t sgo = (size_t)((t) >> 1) * (SGST * 2);                                \
        const int    sho = ((t) & 1) * 64;                                                 \
        const char* gA0 = Ap + sgo + (size_t)row_me * 128 + sho + kb_me;                   \
        const char* gB0 = Bp + sgo + (size_t)row_me * 128 + sho + kb_me;                   \
        char* lA = (char*)(&sA[bufidx][0]) + tid * 16;                                     \
        char* lB = (char*)(&sB[bufidx][0]) + tid * 16;                                     \
        __builtin_amdgcn_global_load_lds((const __attribute__((address_space(1))) void*)gA0,              \
                                         (__attribute__((address_space(3))) void*)lA, 16, 0, 0);          \
        __builtin_amdgcn_global_load_lds((const __attribute__((address_space(1))) void*)(gA0 + 128*128),  \
                                         (__attribute__((address_space(3))) void*)(lA + 8192), 16, 0, 0); \
        __builtin_amdgcn_global_load_lds((const __attribute__((address_space(1))) void*)gB0,              \
                                         (__attribute__((address_space(3))) void*)lB, 16, 0, 0);          \
        __builtin_amdgcn_global_load_lds((const __attribute__((address_space(1))) void*)(gB0 + 128*128),  \
                                         (__attribute__((address_space(3))) void*)(lB + 8192), 16, 0, 0); \
    } while (0)

    STAGE(0, 0);
    asm volatile("s_waitcnt vmcnt(0)" ::: "memory");
    __syncthreads();

#pragma unroll 2
    for (int t = 0; t < NT; ++t) {
        const int cur = t & 1;
        if (t + 1 < NT) STAGE(cur ^ 1, t + 1);   // prefetch next K-slab

        const char* lA = (const char*)(&sA[cur][0]);
        const char* lB = (const char*)(&sB[cur][0]);
        bf16x8 af[8], bfr[4];
#pragma unroll
        for (int mI = 0; mI < 8; ++mI) {
            int row  = wr * 128 + mI * 16 + lrow;
            int byte = (row * 64 + half * 16) ^ (((row >> 1) & 3) << 4);
            af[mI] = *reinterpret_cast<const bf16x8*>(lA + byte);
        }
#pragma unroll
        for (int nI = 0; nI < 4; ++nI) {
            int row  = wc * 64 + nI * 16 + lrow;
            int byte = (row * 64 + half * 16) ^ (((row >> 1) & 3) << 4);
            bfr[nI] = *reinterpret_cast<const bf16x8*>(lB + byte);
        }
#pragma unroll
        for (int mI = 0; mI < 8; ++mI)
#pragma unroll
            for (int nI = 0; nI < 4; ++nI)
                acc[mI][nI] = __builtin_amdgcn_mfma_f32_16x16x32_bf16(af[mI], bfr[nI], acc[mI][nI], 0, 0, 0);

        __syncthreads();   // drains vmcnt+lgkmcnt (buffers safe to swap)
    }
#undef STAGE

    // C/D layout: col = lane&15 (from B), row = (lane>>4)*4 + reg (from A)
    __hip_bfloat16* Op = outer + (size_t)bc * (I_ * I_);
#pragma unroll
    for (int mI = 0; mI < 8; ++mI) {
        int ii = i0 + wr * 128 + mI * 16 + half * 4;
#pragma unroll
        for (int nI = 0; nI < 4; ++nI) {
            int jj = j0 + wc * 64 + nI * 16 + lrow;
#pragma unroll
            for (int r = 0; r < 4; ++r)
                Op[(size_t)(ii + r) * I_ + jj] =
                    __float2bfloat16(acc[mI][nI][r] * (1.f / S_));
        }
    }
}

// ---------------------------------------------------------------------------
// Pass 2: out[b,i,j,c] = bo[c] + sum_c' Wo[c,c'] * outer_scaled[(b,c'),i,j]
// ---------------------------------------------------------------------------
__global__ __launch_bounds__(256) void wo_kernel(
    const __hip_bfloat16* __restrict__ outer,
    const float* __restrict__ Wo, const float* __restrict__ bo,
    float* __restrict__ out)
{
    int tid = blockIdx.x * 256 + threadIdx.x;   // ((b*I + i)*J + j)
    int j  = tid & (I_ - 1);
    int bi = tid >> 9;
    int i  = bi & (I_ - 1);
    int b  = bi >> 9;

    const __hip_bfloat16* ip = outer + ((size_t)(b * C_) * I_ + i) * I_ + j;
    float v[C_];
#pragma unroll
    for (int c = 0; c < C_; ++c) v[c] = __bfloat162float(ip[(size_t)c * (I_ * I_)]);

    float o[C_];
#pragma unroll
    for (int c = 0; c < C_; ++c) {
        float acc = bo[c];
#pragma unroll
        for (int k = 0; k < C_; ++k) acc = fmaf(Wo[c * C_ + k], v[k], acc);
        o[c] = acc;
    }

    float* op = out + (size_t)tid * C_;
#pragma unroll
    for (int vv = 0; vv < 8; ++vv) {
        float4 t4 = { o[4*vv+0], o[4*vv+1], o[4*vv+2], o[4*vv+3] };
        reinterpret_cast<float4*>(op)[vv] = t4;
    }
}

// ---------------------------------------------------------------------------
extern "C" void kernel_launch(void* const* d_in, const int* in_sizes, int n_in,
                              void* d_out, int out_size, void* d_ws, size_t ws_size,
                              hipStream_t stream) {
    const float* m    = (const float*)d_in[0];
    const float* ln_g = (const float*)d_in[1];
    const float* ln_b = (const float*)d_in[2];
    const float* Wa   = (const float*)d_in[3];
    const float* ba   = (const float*)d_in[4];
    const float* Wb   = (const float*)d_in[5];
    const float* bb   = (const float*)d_in[6];
    const float* Wo   = (const float*)d_in[7];
    const float* bo   = (const float*)d_in[8];
    float* out = (float*)d_out;

    const size_t AEL = (size_t)B_ * BST;            // elems per array (padded)
    const size_t nO  = (size_t)B_ * C_ * I_ * I_;   // 16,777,216 elems (32 MiB bf16)
    const size_t need = (AEL * 2 + nO) * sizeof(__hip_bfloat16);  // ~161 MiB
    if (ws_size < need) return;   // diagnostic: output stays zero -> ws too small

    __hip_bfloat16* a_t = (__hip_bfloat16*)d_ws;
    __hip_bfloat16* b_t = a_t + AEL;
    __hip_bfloat16* outer = b_t + AEL;

    ln_proj_kernel<<<B_ * 4 * 128, 256, 0, stream>>>(m, ln_g, ln_b, Wa, ba, Wb, bb, a_t, b_t);
    opm_gemm_kernel<<<B_ * C_ * 4, 512, 0, stream>>>(a_t, b_t, outer);
    wo_kernel<<<(B_ * I_ * I_) / 256, 256, 0, stream>>>(outer, Wo, bo, out);
}